// Round 9
// baseline (185.389 us; speedup 1.0000x reference)
//
#include <hip/hip_runtime.h>
#include <hip/hip_bf16.h>

typedef __attribute__((ext_vector_type(8))) __bf16 bf16x8;
typedef __attribute__((ext_vector_type(4))) __bf16 bf16x4;
typedef __attribute__((ext_vector_type(4))) float f32x4;

#define MFMA16(a, b, c) __builtin_amdgcn_mfma_f32_16x16x32_bf16(a, b, c, 0, 0, 0)

static __device__ __forceinline__ ushort f2b(float f) {
    __bf16 b = (__bf16)f;
    return __builtin_bit_cast(ushort, b);
}
static __device__ __forceinline__ bf16x8 cat44(bf16x4 a, bf16x4 b) {
    bf16x8 r;
    r[0] = a[0]; r[1] = a[1]; r[2] = a[2]; r[3] = a[3];
    r[4] = b[0]; r[5] = b[1]; r[6] = b[2]; r[7] = b[3];
    return r;
}
static __device__ __forceinline__ void gload_lds16(const ushort* g, ushort* l) {
    __builtin_amdgcn_global_load_lds(
        (const __attribute__((address_space(1))) unsigned int*)g,
        (__attribute__((address_space(3))) unsigned int*)l, 16, 0, 0);
}
static __device__ __forceinline__ float exp2_fast(float x) {
    float r;
    asm("v_exp_f32 %0, %1" : "=v"(r) : "v"(x));
    return r;
}

// ---------------- f32 -> bf16 convert (vectorized) ----------------
__global__ void f32_to_bf16_k(const float* __restrict__ in, ushort* __restrict__ out, int n4) {
    int i = blockIdx.x * blockDim.x + threadIdx.x;
    if (i >= n4) return;
    float4 v = reinterpret_cast<const float4*>(in)[i];
    ushort4 o;
    o.x = f2b(v.x); o.y = f2b(v.y); o.z = f2b(v.z); o.w = f2b(v.w);
    reinterpret_cast<ushort4*>(out)[i] = o;
}

// ---------------- all W transposes, LDS-tiled, one launch ----------------
__global__ __launch_bounds__(256)
void transpose_all_k(const float* __restrict__ Wq, const float* __restrict__ Wk,
                     const float* __restrict__ Wv, const float* __restrict__ Wo,
                     ushort* __restrict__ Wqkv, ushort* __restrict__ Wot) {
    __shared__ ushort T[64][72];
    const int bid = blockIdx.x;
    const int job = bid >> 7;
    const int t = bid & 127;
    const float* src; ushort* dst; int K, N;
    if (job == 0)      { src = Wq; dst = Wqkv;                      K = 1024; N = 512; }
    else if (job == 1) { src = Wk; dst = Wqkv + (size_t)512 * 1024; K = 1024; N = 512; }
    else if (job == 2) { src = Wv; dst = Wqkv + (size_t)1024 * 1024; K = 1024; N = 512; }
    else               { src = Wo; dst = Wot;                       K = 512;  N = 1024; }
    const int tn = N >> 6;
    const int bk = t / tn, bn = t - bk * tn;
    const int k0 = bk * 64, n0 = bn * 64;
    const int tid = threadIdx.x;
#pragma unroll
    for (int q = 0; q < 4; ++q) {
        const int lin = tid + 256 * q;
        const int kr = lin >> 4;
        const int n4 = (lin & 15) << 2;
        float4 v = *reinterpret_cast<const float4*>(&src[(size_t)(k0 + kr) * N + n0 + n4]);
        T[n4 + 0][kr] = f2b(v.x);
        T[n4 + 1][kr] = f2b(v.y);
        T[n4 + 2][kr] = f2b(v.z);
        T[n4 + 3][kr] = f2b(v.w);
    }
    __syncthreads();
#pragma unroll
    for (int s = 0; s < 2; ++s) {
        const int lin = tid + 256 * s;
        const int n = lin >> 3;
        const int kc = (lin & 7) << 3;
        ushort4 a, b;
        a.x = T[n][kc + 0]; a.y = T[n][kc + 1]; a.z = T[n][kc + 2]; a.w = T[n][kc + 3];
        b.x = T[n][kc + 4]; b.y = T[n][kc + 5]; b.z = T[n][kc + 6]; b.w = T[n][kc + 7];
        ushort* p = &dst[(size_t)(n0 + n) * K + k0 + kc];
        *reinterpret_cast<ushort4*>(p) = a;
        *reinterpret_cast<ushort4*>(p + 4) = b;
    }
}

// ---------------- tiled GEMM (m97 structure, single-buffer): C = A*Bt^T ----------------
// ROUTE=1 (QKV fused, N=1536): grp0/1 (Q,K) -> per-head row l2norm -> bf16;
// grp2 (V) -> transposed write to Vt[32][64][2048].
template <int F32OUT, int ROUTE>
__global__ __launch_bounds__(256)
void gemm_tile_k(const ushort* __restrict__ A, const ushort* __restrict__ Bt,
                 void* __restrict__ C0, void* __restrict__ C1, void* __restrict__ C2,
                 int M, int N, int K, int nby) {
    __shared__ __align__(16) ushort As[128 * 32];
    __shared__ __align__(16) ushort Bs[128 * 32];
    const int tid = threadIdx.x;
    const int lane = tid & 63;
    const int w = tid >> 6;
    const int l15 = lane & 15, g = lane >> 4;
    const int wr = w >> 1, wc = w & 1;

    const int nwg = gridDim.x;
    const int cpx = nwg >> 3;
    const int bid = blockIdx.x;
    const int swz = (bid & 7) * cpx + (bid >> 3);
    const int bx = swz / nby, by = swz - bx * nby;
    const int rbase = bx * 128, cbase = by * 128;

    const int srow = lane >> 2;
    const int scol = (lane & 3) * 8;
    const ushort* Aw0 = A + (size_t)(rbase + 32 * w + srow) * K + scol;
    const ushort* Bw0 = Bt + (size_t)(cbase + 32 * w + srow) * K + scol;

    f32x4 acc[4][4];
#pragma unroll
    for (int m = 0; m < 4; ++m)
#pragma unroll
        for (int n = 0; n < 4; ++n) acc[m][n] = (f32x4){0, 0, 0, 0};

    const int nk = K >> 5;
    for (int kt = 0; kt < nk; ++kt) {
        const int k0 = kt << 5;
        if (kt) __syncthreads();
        gload_lds16(Aw0 + k0,          &As[(32 * w) * 32]);
        gload_lds16(Aw0 + 16 * K + k0, &As[(32 * w + 16) * 32]);
        gload_lds16(Bw0 + k0,          &Bs[(32 * w) * 32]);
        gload_lds16(Bw0 + 16 * K + k0, &Bs[(32 * w + 16) * 32]);
        __syncthreads();
        bf16x8 af[4], bf[4];
#pragma unroll
        for (int m = 0; m < 4; ++m)
            af[m] = *reinterpret_cast<const bf16x8*>(&As[(64 * wr + 16 * m + l15) * 32 + 8 * g]);
#pragma unroll
        for (int n = 0; n < 4; ++n)
            bf[n] = *reinterpret_cast<const bf16x8*>(&Bs[(64 * wc + 16 * n + l15) * 32 + 8 * g]);
#pragma unroll
        for (int m = 0; m < 4; ++m)
#pragma unroll
            for (int n = 0; n < 4; ++n)
                acc[m][n] = MFMA16(af[m], bf[n], acc[m][n]);
    }

    if (ROUTE) {
        const int col0 = cbase + 64 * wc;     // wave-uniform, 64-aligned => one head
        const int grp = col0 >> 9;            // 0=Q,1=K,2=V
        const int co0 = col0 & 511;
        if (grp == 2) {
            const int h = co0 >> 6;
#pragma unroll
            for (int m = 0; m < 4; ++m) {
                const int row = rbase + 64 * wr + 16 * m + 4 * g;
                const int bb = row >> 11;
                const int tok = row & 2047;
#pragma unroll
                for (int n = 0; n < 4; ++n) {
                    const int d = 16 * n + l15;
                    bf16x4 wv;
#pragma unroll
                    for (int r = 0; r < 4; ++r) wv[r] = (__bf16)acc[m][n][r];
                    ushort* dst = (ushort*)C2 + (((size_t)(bb * 8 + h) * 64 + d) * 2048 + tok);
                    *reinterpret_cast<bf16x4*>(dst) = wv;
                }
            }
        } else {
            ushort* Cg = (ushort*)(grp == 0 ? C0 : C1);
#pragma unroll
            for (int m = 0; m < 4; ++m) {
                f32x4 ss = {0, 0, 0, 0};
#pragma unroll
                for (int n = 0; n < 4; ++n)
#pragma unroll
                    for (int r = 0; r < 4; ++r) ss[r] += acc[m][n][r] * acc[m][n][r];
#pragma unroll
                for (int r = 0; r < 4; ++r) {
                    float s = ss[r];
                    s += __shfl_xor(s, 1);
                    s += __shfl_xor(s, 2);
                    s += __shfl_xor(s, 4);
                    s += __shfl_xor(s, 8);
                    ss[r] = 1.0f / fmaxf(sqrtf(s), 1e-12f);
                }
                const int row = rbase + 64 * wr + 16 * m + 4 * g;
#pragma unroll
                for (int n = 0; n < 4; ++n) {
                    const int co = co0 + 16 * n + l15;
#pragma unroll
                    for (int r = 0; r < 4; ++r)
                        Cg[(size_t)(row + r) * 512 + co] = f2b(acc[m][n][r] * ss[r]);
                }
            }
        }
    } else {
#pragma unroll
        for (int m = 0; m < 4; ++m)
#pragma unroll
            for (int n = 0; n < 4; ++n) {
                const int row = rbase + 64 * wr + 16 * m + 4 * g;
                const int col = cbase + 64 * wc + 16 * n + l15;
                if (F32OUT) {
#pragma unroll
                    for (int r = 0; r < 4; ++r)
                        reinterpret_cast<float*>(C0)[(size_t)(row + r) * N + col] = acc[m][n][r];
                } else {
#pragma unroll
                    for (int r = 0; r < 4; ++r)
                        reinterpret_cast<ushort*>(C0)[(size_t)(row + r) * N + col] = f2b(acc[m][n][r]);
                }
            }
    }
}

// ---------------- causal cosine-sim flash attention (v7: kv-split, 4 waves) ----------------
// Fixed-offset softmax (S<=8) is ADDITIVE over kv-tiles -> split each q-pair's
// kv-range across two waves in the same block (front half [0,mid), back half
// [mid,ntb)), combine partial (acc,l) in LDS at the end. 4 waves/block, 4
// tiles staged/step (K/V x half), 16 waves/CU.
__global__ __launch_bounds__(256, 4)
void flash_attn_k(const ushort* __restrict__ Q, const ushort* __restrict__ K,
                  const ushort* __restrict__ Vg, ushort* __restrict__ O) {
    __shared__ __align__(16) ushort S[4][4096];  // [0]=K front, [1]=V front, [2]=K back, [3]=V back
    const int tid = threadIdx.x;      // 0..255
    const int lane = tid & 63;
    const int wave = tid >> 6;        // 0..3
    const int half = wave >> 1;       // 0 front, 1 back
    const int wsel = wave & 1;        // pair slot in block
    const int l15 = lane & 15;
    const int g = lane >> 4;
    const int bh = blockIdx.x;
    const int b = bh >> 3, h = bh & 7;
    const int j = blockIdx.y;                   // 0..31
    const int ytrue = (j < 16) ? j : 47 - j;
    const int wglob = ytrue * 2 + wsel;         // 0..63
    const int c0 = wglob;
    const int c1 = 127 - wglob;
    const int q0 = c0 * 16 + l15;
    const int q1 = c1 * 16 + l15;
    const int nt0 = (c0 * 16 + 79) >> 6;
    const int nt1 = (c1 * 16 + 79) >> 6;
    const int ntb = ((127 - 2 * ytrue) * 16 + 79) >> 6;  // block tile count
    const int mid = (ntb + 1) >> 1;
    const int tbase = half ? mid : 0;

    const float CEXP = 11.5415603f;  // 8*log2(e)

    const ushort* Qb = Q + (size_t)(b * 2048) * 512 + h * 64;
    const ushort* Kb = K + (size_t)(b * 2048) * 512 + h * 64;
    const ushort* Vb = Vg + (size_t)bh * 64 * 2048;

    // staging: tile = 512 x 16B slots; thread covers slots {tid, tid+256}
    int srow[2], ssc[2];
#pragma unroll
    for (int i = 0; i < 2; ++i) {
        const int s = tid + 256 * i;
        srow[i] = s >> 3;
        ssc[i] = (s & 7) ^ (srow[i] & 7);
    }

    bf16x8 qf0[2], qf1[2];
#pragma unroll
    for (int kh = 0; kh < 2; ++kh) {
        qf0[kh] = *reinterpret_cast<const bf16x8*>(Qb + (size_t)q0 * 512 + 32 * kh + 8 * g);
        qf1[kh] = *reinterpret_cast<const bf16x8*>(Qb + (size_t)q1 * 512 + 32 * kh + 8 * g);
    }

    bf16x8 ones;
#pragma unroll
    for (int i = 0; i < 8; ++i) ones[i] = (__bf16)1.0f;

    f32x4 acc0[4], acc1[4];
#pragma unroll
    for (int d = 0; d < 4; ++d) {
        acc0[d] = (f32x4){0, 0, 0, 0};
        acc1[d] = (f32x4){0, 0, 0, 0};
    }
    f32x4 lac0 = {0, 0, 0, 0}, lac1 = {0, 0, 0, 0};

    const ushort* Kt = S[half * 2];
    const ushort* Vt = S[half * 2 + 1];

    for (int s = 0; s < mid; ++s) {
        if (s) __syncthreads();
        // stage front tiles (t=s) and back tiles (t=mid+s) — block-uniform guards
#pragma unroll
        for (int i = 0; i < 2; ++i) {
            const int sl = tid + 256 * i;
            gload_lds16(Kb + (size_t)(s * 64 + srow[i]) * 512 + ssc[i] * 8, &S[0][sl * 8]);
            gload_lds16(Vb + (size_t)srow[i] * 2048 + s * 64 + ssc[i] * 8, &S[1][sl * 8]);
        }
        if (mid + s < ntb) {
#pragma unroll
            for (int i = 0; i < 2; ++i) {
                const int sl = tid + 256 * i;
                gload_lds16(Kb + (size_t)((mid + s) * 64 + srow[i]) * 512 + ssc[i] * 8, &S[2][sl * 8]);
                gload_lds16(Vb + (size_t)srow[i] * 2048 + (mid + s) * 64 + ssc[i] * 8, &S[3][sl * 8]);
            }
        }
        __syncthreads();

        const int t = tbase + s;
        if (t >= nt1) continue;  // nothing to do (nt0 <= nt1)
        const bool act0 = (t < nt0);
        const bool mk0 = (t == nt0 - 1);
        const bool mk1 = (t == nt1 - 1);

        bf16x8 af[4][2];
#pragma unroll
        for (int jt = 0; jt < 4; ++jt)
#pragma unroll
            for (int kh = 0; kh < 2; ++kh) {
                const int row = jt * 16 + l15;
                const int chunk = (g + 4 * kh) ^ (row & 7);
                af[jt][kh] = *reinterpret_cast<const bf16x8*>(&Kt[row * 64 + chunk * 8]);
            }
        bf16x4 vf[4][2][2];
#pragma unroll
        for (int d = 0; d < 4; ++d)
#pragma unroll
            for (int kk = 0; kk < 2; ++kk)
#pragma unroll
                for (int th = 0; th < 2; ++th) {
                    const int dr = d * 16 + l15;
                    const int chunk = ((g >> 1) + 2 * th + 4 * kk) ^ (dr & 7);
                    vf[d][kk][th] = *reinterpret_cast<const bf16x4*>(
                        &Vt[dr * 64 + chunk * 8 + (g & 1) * 4]);
                }

        // QK^T for BOTH q-tiles first: softmax1 VALU overlaps tile0 MFMA latency
        f32x4 s1[4], s0[4];
#pragma unroll
        for (int jt = 0; jt < 4; ++jt) {
            f32x4 z = {0, 0, 0, 0};
            z = MFMA16(af[jt][0], qf1[0], z);
            s1[jt] = MFMA16(af[jt][1], qf1[1], z);
        }
        if (act0) {
#pragma unroll
            for (int jt = 0; jt < 4; ++jt) {
                f32x4 z = {0, 0, 0, 0};
                z = MFMA16(af[jt][0], qf0[0], z);
                s0[jt] = MFMA16(af[jt][1], qf0[1], z);
            }
        }

        bf16x8 pt1[2];
#pragma unroll
        for (int jt = 0; jt < 4; ++jt) {
#pragma unroll
            for (int r = 0; r < 4; ++r) {
                float p = exp2_fast(fmaf(s1[jt][r], CEXP, -CEXP));
                if (mk1) {
                    int jj = t * 64 + jt * 16 + 4 * g + r;
                    p = (jj <= q1) ? p : 0.0f;
                }
                pt1[jt >> 1][(jt & 1) * 4 + r] = (__bf16)p;
            }
        }

        __builtin_amdgcn_s_setprio(1);
#pragma unroll
        for (int d = 0; d < 4; ++d) {
            bf16x8 v0 = cat44(vf[d][0][0], vf[d][0][1]);
            bf16x8 v1 = cat44(vf[d][1][0], vf[d][1][1]);
            acc1[d] = MFMA16(v0, pt1[0], acc1[d]);
            acc1[d] = MFMA16(v1, pt1[1], acc1[d]);
        }
        lac1 = MFMA16(ones, pt1[0], lac1);
        lac1 = MFMA16(ones, pt1[1], lac1);
        __builtin_amdgcn_s_setprio(0);

        if (act0) {
            bf16x8 pt0[2];
#pragma unroll
            for (int jt = 0; jt < 4; ++jt) {
#pragma unroll
                for (int r = 0; r < 4; ++r) {
                    float p = exp2_fast(fmaf(s0[jt][r], CEXP, -CEXP));
                    if (mk0) {
                        int jj = t * 64 + jt * 16 + 4 * g + r;
                        p = (jj <= q0) ? p : 0.0f;
                    }
                    pt0[jt >> 1][(jt & 1) * 4 + r] = (__bf16)p;
                }
            }
            __builtin_amdgcn_s_setprio(1);
#pragma unroll
            for (int d = 0; d < 4; ++d) {
                bf16x8 v0 = cat44(vf[d][0][0], vf[d][0][1]);
                bf16x8 v1 = cat44(vf[d][1][0], vf[d][1][1]);
                acc0[d] = MFMA16(v0, pt0[0], acc0[d]);
                acc0[d] = MFMA16(v1, pt0[1], acc0[d]);
            }
            lac0 = MFMA16(ones, pt0[0], lac0);
            lac0 = MFMA16(ones, pt0[1], lac0);
            __builtin_amdgcn_s_setprio(0);
        }
    }

    // ---- combine halves in LDS (tiles dead now) ----
    __syncthreads();
    if (half == 1) {
        float* dst = (float*)S[wsel * 2];   // 8KB = 2048 floats (two q-tiles)
#pragma unroll
        for (int d = 0; d < 4; ++d)
#pragma unroll
            for (int r = 0; r < 4; ++r) {
                dst[(d * 4 + r) * 64 + lane] = acc1[d][r];
                dst[1024 + (d * 4 + r) * 64 + lane] = acc0[d][r];
            }
        if (g == 0) {
            float* lf = (float*)S[1];  // wait: S[1] is wsel0's dst region half
            // use S[3] (back-V) for l values instead — always free here
            lf = (float*)S[3];
            lf[wsel * 32 + l15] = lac1[0];
            lf[wsel * 32 + 16 + l15] = lac0[0];
        }
    }
    __syncthreads();
    if (half == 0) {
        const float* src = (const float*)S[wsel * 2];
        const float* lf = (const float*)S[3];
        const float l1 = lac1[0] + lf[wsel * 32 + l15];
        const float l0 = lac0[0] + lf[wsel * 32 + 16 + l15];
#pragma unroll
        for (int d = 0; d < 4; ++d)
#pragma unroll
            for (int r = 0; r < 4; ++r) {
                acc1[d][r] += src[(d * 4 + r) * 64 + lane];
                acc0[d][r] += src[1024 + (d * 4 + r) * 64 + lane];
            }
        auto fin = [&](f32x4 (&acc)[4], float ls, int qr) {
            float inv = 1.0f / ls;
            ushort* Ob = O + (size_t)(b * 2048 + qr) * 512 + h * 64;
#pragma unroll
            for (int d = 0; d < 4; ++d) {
                bf16x4 w;
#pragma unroll
                for (int r = 0; r < 4; ++r) w[r] = (__bf16)(acc[d][r] * inv);
                *reinterpret_cast<bf16x4*>(Ob + d * 16 + 4 * g) = w;
            }
        };
        fin(acc1, l1, q1);
        fin(acc0, l0, q0);
    }
}

extern "C" void kernel_launch(void* const* d_in, const int* in_sizes, int n_in,
                              void* d_out, int out_size, void* d_ws, size_t ws_size,
                              hipStream_t stream) {
    const float* x  = (const float*)d_in[0];
    const float* Wq = (const float*)d_in[1];
    const float* Wk = (const float*)d_in[2];
    const float* Wv = (const float*)d_in[3];
    const float* Wo = (const float*)d_in[4];
    float* out = (float*)d_out;

    char* ws = (char*)d_ws;
    ushort* xb  = (ushort*)ws; ws += (size_t)8192 * 1024 * 2;   // 16 MB
    ushort* Wqt = (ushort*)ws; ws += (size_t)1536 * 1024 * 2;   // fused [1536][1024]
    ushort* Wot = (ushort*)ws; ws += (size_t)1024 * 512 * 2;
    ushort* Qm  = (ushort*)ws; ws += (size_t)8192 * 512 * 2;
    ushort* Km  = (ushort*)ws; ws += (size_t)8192 * 512 * 2;
    ushort* Vtm = (ushort*)ws; ws += (size_t)8192 * 512 * 2;
    ushort* Om  = xb;  // reuse: xb dead after QKV GEMM

    f32_to_bf16_k<<<8192, 256, 0, stream>>>(x, xb, 2097152);
    transpose_all_k<<<512, 256, 0, stream>>>(Wq, Wk, Wv, Wo, Wqt, Wot);

    // fused QKV GEMM + l2norm(Q,K) + V transpose: -> Qm | Km | Vtm
    gemm_tile_k<0, 1><<<768, 256, 0, stream>>>(xb, Wqt, Qm, Km, Vtm, 8192, 1536, 1024, 12);

    flash_attn_k<<<dim3(32, 32), 256, 0, stream>>>(Qm, Km, Vtm, Om);

    // out projection: [8192][512] x [1024][512]^T -> out (f32)
    gemm_tile_k<1, 0><<<512, 256, 0, stream>>>(Om, Wot, out, nullptr, nullptr, 8192, 1024, 512, 8);
}

// Round 10
// 116.242 us; speedup vs baseline: 1.5949x; 1.5949x over previous
//
#include <hip/hip_runtime.h>
#include <hip/hip_bf16.h>

typedef __attribute__((ext_vector_type(8))) __bf16 bf16x8;
typedef __attribute__((ext_vector_type(4))) __bf16 bf16x4;
typedef __attribute__((ext_vector_type(4))) float f32x4;

#define MFMA16(a, b, c) __builtin_amdgcn_mfma_f32_16x16x32_bf16(a, b, c, 0, 0, 0)

static __device__ __forceinline__ ushort f2b(float f) {
    __bf16 b = (__bf16)f;
    return __builtin_bit_cast(ushort, b);
}
static __device__ __forceinline__ bf16x8 cat44(bf16x4 a, bf16x4 b) {
    bf16x8 r;
    r[0] = a[0]; r[1] = a[1]; r[2] = a[2]; r[3] = a[3];
    r[4] = b[0]; r[5] = b[1]; r[6] = b[2]; r[7] = b[3];
    return r;
}
static __device__ __forceinline__ void gload_lds16(const ushort* g, ushort* l) {
    __builtin_amdgcn_global_load_lds(
        (const __attribute__((address_space(1))) unsigned int*)g,
        (__attribute__((address_space(3))) unsigned int*)l, 16, 0, 0);
}
static __device__ __forceinline__ float exp2_fast(float x) {
    float r;
    asm("v_exp_f32 %0, %1" : "=v"(r) : "v"(x));
    return r;
}

// ---------------- f32 -> bf16 convert (vectorized) ----------------
__global__ void f32_to_bf16_k(const float* __restrict__ in, ushort* __restrict__ out, int n4) {
    int i = blockIdx.x * blockDim.x + threadIdx.x;
    if (i >= n4) return;
    float4 v = reinterpret_cast<const float4*>(in)[i];
    ushort4 o;
    o.x = f2b(v.x); o.y = f2b(v.y); o.z = f2b(v.z); o.w = f2b(v.w);
    reinterpret_cast<ushort4*>(out)[i] = o;
}

// ---------------- all W transposes, LDS-tiled, one launch ----------------
__global__ __launch_bounds__(256)
void transpose_all_k(const float* __restrict__ Wq, const float* __restrict__ Wk,
                     const float* __restrict__ Wv, const float* __restrict__ Wo,
                     ushort* __restrict__ Wqkv, ushort* __restrict__ Wot) {
    __shared__ ushort T[64][72];
    const int bid = blockIdx.x;
    const int job = bid >> 7;
    const int t = bid & 127;
    const float* src; ushort* dst; int K, N;
    if (job == 0)      { src = Wq; dst = Wqkv;                      K = 1024; N = 512; }
    else if (job == 1) { src = Wk; dst = Wqkv + (size_t)512 * 1024; K = 1024; N = 512; }
    else if (job == 2) { src = Wv; dst = Wqkv + (size_t)1024 * 1024; K = 1024; N = 512; }
    else               { src = Wo; dst = Wot;                       K = 512;  N = 1024; }
    const int tn = N >> 6;
    const int bk = t / tn, bn = t - bk * tn;
    const int k0 = bk * 64, n0 = bn * 64;
    const int tid = threadIdx.x;
#pragma unroll
    for (int q = 0; q < 4; ++q) {
        const int lin = tid + 256 * q;
        const int kr = lin >> 4;
        const int n4 = (lin & 15) << 2;
        float4 v = *reinterpret_cast<const float4*>(&src[(size_t)(k0 + kr) * N + n0 + n4]);
        T[n4 + 0][kr] = f2b(v.x);
        T[n4 + 1][kr] = f2b(v.y);
        T[n4 + 2][kr] = f2b(v.z);
        T[n4 + 3][kr] = f2b(v.w);
    }
    __syncthreads();
#pragma unroll
    for (int s = 0; s < 2; ++s) {
        const int lin = tid + 256 * s;
        const int n = lin >> 3;
        const int kc = (lin & 7) << 3;
        ushort4 a, b;
        a.x = T[n][kc + 0]; a.y = T[n][kc + 1]; a.z = T[n][kc + 2]; a.w = T[n][kc + 3];
        b.x = T[n][kc + 4]; b.y = T[n][kc + 5]; b.z = T[n][kc + 6]; b.w = T[n][kc + 7];
        ushort* p = &dst[(size_t)(n0 + n) * K + k0 + kc];
        *reinterpret_cast<ushort4*>(p) = a;
        *reinterpret_cast<ushort4*>(p + 4) = b;
    }
}

// ---------------- tiled GEMM (m97 structure, single-buffer): C = A*Bt^T ----------------
// ROUTE=1 (QKV fused, N=1536): grp0/1 (Q,K) -> per-head row l2norm -> bf16;
// grp2 (V) -> transposed write to Vt[32][64][2048].
template <int F32OUT, int ROUTE>
__global__ __launch_bounds__(256)
void gemm_tile_k(const ushort* __restrict__ A, const ushort* __restrict__ Bt,
                 void* __restrict__ C0, void* __restrict__ C1, void* __restrict__ C2,
                 int M, int N, int K, int nby) {
    __shared__ __align__(16) ushort As[128 * 32];
    __shared__ __align__(16) ushort Bs[128 * 32];
    const int tid = threadIdx.x;
    const int lane = tid & 63;
    const int w = tid >> 6;
    const int l15 = lane & 15, g = lane >> 4;
    const int wr = w >> 1, wc = w & 1;

    const int nwg = gridDim.x;
    const int cpx = nwg >> 3;
    const int bid = blockIdx.x;
    const int swz = (bid & 7) * cpx + (bid >> 3);
    const int bx = swz / nby, by = swz - bx * nby;
    const int rbase = bx * 128, cbase = by * 128;

    const int srow = lane >> 2;
    const int scol = (lane & 3) * 8;
    const ushort* Aw0 = A + (size_t)(rbase + 32 * w + srow) * K + scol;
    const ushort* Bw0 = Bt + (size_t)(cbase + 32 * w + srow) * K + scol;

    f32x4 acc[4][4];
#pragma unroll
    for (int m = 0; m < 4; ++m)
#pragma unroll
        for (int n = 0; n < 4; ++n) acc[m][n] = (f32x4){0, 0, 0, 0};

    const int nk = K >> 5;
    for (int kt = 0; kt < nk; ++kt) {
        const int k0 = kt << 5;
        if (kt) __syncthreads();
        gload_lds16(Aw0 + k0,          &As[(32 * w) * 32]);
        gload_lds16(Aw0 + 16 * K + k0, &As[(32 * w + 16) * 32]);
        gload_lds16(Bw0 + k0,          &Bs[(32 * w) * 32]);
        gload_lds16(Bw0 + 16 * K + k0, &Bs[(32 * w + 16) * 32]);
        __syncthreads();
        bf16x8 af[4], bf[4];
#pragma unroll
        for (int m = 0; m < 4; ++m)
            af[m] = *reinterpret_cast<const bf16x8*>(&As[(64 * wr + 16 * m + l15) * 32 + 8 * g]);
#pragma unroll
        for (int n = 0; n < 4; ++n)
            bf[n] = *reinterpret_cast<const bf16x8*>(&Bs[(64 * wc + 16 * n + l15) * 32 + 8 * g]);
#pragma unroll
        for (int m = 0; m < 4; ++m)
#pragma unroll
            for (int n = 0; n < 4; ++n)
                acc[m][n] = MFMA16(af[m], bf[n], acc[m][n]);
    }

    if (ROUTE) {
        const int col0 = cbase + 64 * wc;     // wave-uniform, 64-aligned => one head
        const int grp = col0 >> 9;            // 0=Q,1=K,2=V
        const int co0 = col0 & 511;
        if (grp == 2) {
            const int h = co0 >> 6;
#pragma unroll
            for (int m = 0; m < 4; ++m) {
                const int row = rbase + 64 * wr + 16 * m + 4 * g;
                const int bb = row >> 11;
                const int tok = row & 2047;
#pragma unroll
                for (int n = 0; n < 4; ++n) {
                    const int d = 16 * n + l15;
                    bf16x4 wv;
#pragma unroll
                    for (int r = 0; r < 4; ++r) wv[r] = (__bf16)acc[m][n][r];
                    ushort* dst = (ushort*)C2 + (((size_t)(bb * 8 + h) * 64 + d) * 2048 + tok);
                    *reinterpret_cast<bf16x4*>(dst) = wv;
                }
            }
        } else {
            ushort* Cg = (ushort*)(grp == 0 ? C0 : C1);
#pragma unroll
            for (int m = 0; m < 4; ++m) {
                f32x4 ss = {0, 0, 0, 0};
#pragma unroll
                for (int n = 0; n < 4; ++n)
#pragma unroll
                    for (int r = 0; r < 4; ++r) ss[r] += acc[m][n][r] * acc[m][n][r];
#pragma unroll
                for (int r = 0; r < 4; ++r) {
                    float s = ss[r];
                    s += __shfl_xor(s, 1);
                    s += __shfl_xor(s, 2);
                    s += __shfl_xor(s, 4);
                    s += __shfl_xor(s, 8);
                    ss[r] = 1.0f / fmaxf(sqrtf(s), 1e-12f);
                }
                const int row = rbase + 64 * wr + 16 * m + 4 * g;
#pragma unroll
                for (int n = 0; n < 4; ++n) {
                    const int co = co0 + 16 * n + l15;
#pragma unroll
                    for (int r = 0; r < 4; ++r)
                        Cg[(size_t)(row + r) * 512 + co] = f2b(acc[m][n][r] * ss[r]);
                }
            }
        }
    } else {
#pragma unroll
        for (int m = 0; m < 4; ++m)
#pragma unroll
            for (int n = 0; n < 4; ++n) {
                const int row = rbase + 64 * wr + 16 * m + 4 * g;
                const int col = cbase + 64 * wc + 16 * n + l15;
                if (F32OUT) {
#pragma unroll
                    for (int r = 0; r < 4; ++r)
                        reinterpret_cast<float*>(C0)[(size_t)(row + r) * N + col] = acc[m][n][r];
                } else {
#pragma unroll
                    for (int r = 0; r < 4; ++r)
                        reinterpret_cast<ushort*>(C0)[(size_t)(row + r) * N + col] = f2b(acc[m][n][r]);
                }
            }
    }
}

// ---------------- causal cosine-sim flash attention (v8: kv-split, no VGPR cap) ----------------
// Round-9 structure with __launch_bounds__(256,2): the (256,4) variant split the
// unified file 64 VGPR + 64 AGPR and spilled ~450MB/dispatch to scratch. Cap 256
// lets the body compile at its natural ~100-128 VGPR (round-8 body = 100) ->
// no spill, 4 waves/SIMD achievable at runtime; LDS 32KB x 4 blocks/CU = 128KB.
__global__ __launch_bounds__(256, 2)
void flash_attn_k(const ushort* __restrict__ Q, const ushort* __restrict__ K,
                  const ushort* __restrict__ Vg, ushort* __restrict__ O) {
    __shared__ __align__(16) ushort S[4][4096];  // [0]=K front, [1]=V front, [2]=K back, [3]=V back
    const int tid = threadIdx.x;      // 0..255
    const int lane = tid & 63;
    const int wave = tid >> 6;        // 0..3
    const int half = wave >> 1;       // 0 front, 1 back
    const int wsel = wave & 1;        // pair slot in block
    const int l15 = lane & 15;
    const int g = lane >> 4;
    const int bh = blockIdx.x;
    const int b = bh >> 3, h = bh & 7;
    const int j = blockIdx.y;                   // 0..31
    const int ytrue = (j < 16) ? j : 47 - j;
    const int wglob = ytrue * 2 + wsel;         // 0..63
    const int c0 = wglob;
    const int c1 = 127 - wglob;
    const int q0 = c0 * 16 + l15;
    const int q1 = c1 * 16 + l15;
    const int nt0 = (c0 * 16 + 79) >> 6;
    const int nt1 = (c1 * 16 + 79) >> 6;
    const int ntb = ((127 - 2 * ytrue) * 16 + 79) >> 6;  // block tile count
    const int mid = (ntb + 1) >> 1;
    const int tbase = half ? mid : 0;

    const float CEXP = 11.5415603f;  // 8*log2(e)

    const ushort* Qb = Q + (size_t)(b * 2048) * 512 + h * 64;
    const ushort* Kb = K + (size_t)(b * 2048) * 512 + h * 64;
    const ushort* Vb = Vg + (size_t)bh * 64 * 2048;

    // staging: tile = 512 x 16B slots; thread covers slots {tid, tid+256}
    int srow[2], ssc[2];
#pragma unroll
    for (int i = 0; i < 2; ++i) {
        const int s = tid + 256 * i;
        srow[i] = s >> 3;
        ssc[i] = (s & 7) ^ (srow[i] & 7);
    }

    bf16x8 qf0[2], qf1[2];
#pragma unroll
    for (int kh = 0; kh < 2; ++kh) {
        qf0[kh] = *reinterpret_cast<const bf16x8*>(Qb + (size_t)q0 * 512 + 32 * kh + 8 * g);
        qf1[kh] = *reinterpret_cast<const bf16x8*>(Qb + (size_t)q1 * 512 + 32 * kh + 8 * g);
    }

    bf16x8 ones;
#pragma unroll
    for (int i = 0; i < 8; ++i) ones[i] = (__bf16)1.0f;

    f32x4 acc0[4], acc1[4];
#pragma unroll
    for (int d = 0; d < 4; ++d) {
        acc0[d] = (f32x4){0, 0, 0, 0};
        acc1[d] = (f32x4){0, 0, 0, 0};
    }
    f32x4 lac0 = {0, 0, 0, 0}, lac1 = {0, 0, 0, 0};

    const ushort* Kt = S[half * 2];
    const ushort* Vt = S[half * 2 + 1];

    for (int s = 0; s < mid; ++s) {
        if (s) __syncthreads();
        // stage front tiles (t=s) and back tiles (t=mid+s) — block-uniform guards
#pragma unroll
        for (int i = 0; i < 2; ++i) {
            const int sl = tid + 256 * i;
            gload_lds16(Kb + (size_t)(s * 64 + srow[i]) * 512 + ssc[i] * 8, &S[0][sl * 8]);
            gload_lds16(Vb + (size_t)srow[i] * 2048 + s * 64 + ssc[i] * 8, &S[1][sl * 8]);
        }
        if (mid + s < ntb) {
#pragma unroll
            for (int i = 0; i < 2; ++i) {
                const int sl = tid + 256 * i;
                gload_lds16(Kb + (size_t)((mid + s) * 64 + srow[i]) * 512 + ssc[i] * 8, &S[2][sl * 8]);
                gload_lds16(Vb + (size_t)srow[i] * 2048 + (mid + s) * 64 + ssc[i] * 8, &S[3][sl * 8]);
            }
        }
        __syncthreads();

        const int t = tbase + s;
        if (t >= nt1) continue;  // nothing to do (nt0 <= nt1)
        const bool act0 = (t < nt0);
        const bool mk0 = (t == nt0 - 1);
        const bool mk1 = (t == nt1 - 1);

        bf16x8 af[4][2];
#pragma unroll
        for (int jt = 0; jt < 4; ++jt)
#pragma unroll
            for (int kh = 0; kh < 2; ++kh) {
                const int row = jt * 16 + l15;
                const int chunk = (g + 4 * kh) ^ (row & 7);
                af[jt][kh] = *reinterpret_cast<const bf16x8*>(&Kt[row * 64 + chunk * 8]);
            }
        bf16x4 vf[4][2][2];
#pragma unroll
        for (int d = 0; d < 4; ++d)
#pragma unroll
            for (int kk = 0; kk < 2; ++kk)
#pragma unroll
                for (int th = 0; th < 2; ++th) {
                    const int dr = d * 16 + l15;
                    const int chunk = ((g >> 1) + 2 * th + 4 * kk) ^ (dr & 7);
                    vf[d][kk][th] = *reinterpret_cast<const bf16x4*>(
                        &Vt[dr * 64 + chunk * 8 + (g & 1) * 4]);
                }

        // QK^T for BOTH q-tiles first: softmax1 VALU overlaps tile0 MFMA latency
        f32x4 s1[4], s0[4];
#pragma unroll
        for (int jt = 0; jt < 4; ++jt) {
            f32x4 z = {0, 0, 0, 0};
            z = MFMA16(af[jt][0], qf1[0], z);
            s1[jt] = MFMA16(af[jt][1], qf1[1], z);
        }
        if (act0) {
#pragma unroll
            for (int jt = 0; jt < 4; ++jt) {
                f32x4 z = {0, 0, 0, 0};
                z = MFMA16(af[jt][0], qf0[0], z);
                s0[jt] = MFMA16(af[jt][1], qf0[1], z);
            }
        }

        bf16x8 pt1[2];
#pragma unroll
        for (int jt = 0; jt < 4; ++jt) {
#pragma unroll
            for (int r = 0; r < 4; ++r) {
                float p = exp2_fast(fmaf(s1[jt][r], CEXP, -CEXP));
                if (mk1) {
                    int jj = t * 64 + jt * 16 + 4 * g + r;
                    p = (jj <= q1) ? p : 0.0f;
                }
                pt1[jt >> 1][(jt & 1) * 4 + r] = (__bf16)p;
            }
        }

        __builtin_amdgcn_s_setprio(1);
#pragma unroll
        for (int d = 0; d < 4; ++d) {
            bf16x8 v0 = cat44(vf[d][0][0], vf[d][0][1]);
            bf16x8 v1 = cat44(vf[d][1][0], vf[d][1][1]);
            acc1[d] = MFMA16(v0, pt1[0], acc1[d]);
            acc1[d] = MFMA16(v1, pt1[1], acc1[d]);
        }
        lac1 = MFMA16(ones, pt1[0], lac1);
        lac1 = MFMA16(ones, pt1[1], lac1);
        __builtin_amdgcn_s_setprio(0);

        if (act0) {
            bf16x8 pt0[2];
#pragma unroll
            for (int jt = 0; jt < 4; ++jt) {
#pragma unroll
                for (int r = 0; r < 4; ++r) {
                    float p = exp2_fast(fmaf(s0[jt][r], CEXP, -CEXP));
                    if (mk0) {
                        int jj = t * 64 + jt * 16 + 4 * g + r;
                        p = (jj <= q0) ? p : 0.0f;
                    }
                    pt0[jt >> 1][(jt & 1) * 4 + r] = (__bf16)p;
                }
            }
            __builtin_amdgcn_s_setprio(1);
#pragma unroll
            for (int d = 0; d < 4; ++d) {
                bf16x8 v0 = cat44(vf[d][0][0], vf[d][0][1]);
                bf16x8 v1 = cat44(vf[d][1][0], vf[d][1][1]);
                acc0[d] = MFMA16(v0, pt0[0], acc0[d]);
                acc0[d] = MFMA16(v1, pt0[1], acc0[d]);
            }
            lac0 = MFMA16(ones, pt0[0], lac0);
            lac0 = MFMA16(ones, pt0[1], lac0);
            __builtin_amdgcn_s_setprio(0);
        }
    }

    // ---- combine halves in LDS (tiles dead now) ----
    __syncthreads();
    if (half == 1) {
        float* dst = (float*)S[wsel * 2];   // 8KB region per pair slot
#pragma unroll
        for (int d = 0; d < 4; ++d)
#pragma unroll
            for (int r = 0; r < 4; ++r) {
                dst[(d * 4 + r) * 64 + lane] = acc1[d][r];
                dst[1024 + (d * 4 + r) * 64 + lane] = acc0[d][r];
            }
        if (g == 0) {
            float* lf = (float*)S[3];  // back-V tile: free here
            lf[wsel * 32 + l15] = lac1[0];
            lf[wsel * 32 + 16 + l15] = lac0[0];
        }
    }
    __syncthreads();
    if (half == 0) {
        const float* src = (const float*)S[wsel * 2];
        const float* lf = (const float*)S[3];
        const float l1 = lac1[0] + lf[wsel * 32 + l15];
        const float l0 = lac0[0] + lf[wsel * 32 + 16 + l15];
#pragma unroll
        for (int d = 0; d < 4; ++d)
#pragma unroll
            for (int r = 0; r < 4; ++r) {
                acc1[d][r] += src[(d * 4 + r) * 64 + lane];
                acc0[d][r] += src[1024 + (d * 4 + r) * 64 + lane];
            }
        auto fin = [&](f32x4 (&acc)[4], float ls, int qr) {
            float inv = 1.0f / ls;
            ushort* Ob = O + (size_t)(b * 2048 + qr) * 512 + h * 64;
#pragma unroll
            for (int d = 0; d < 4; ++d) {
                bf16x4 w;
#pragma unroll
                for (int r = 0; r < 4; ++r) w[r] = (__bf16)(acc[d][r] * inv);
                *reinterpret_cast<bf16x4*>(Ob + d * 16 + 4 * g) = w;
            }
        };
        fin(acc1, l1, q1);
        fin(acc0, l0, q0);
    }
}

extern "C" void kernel_launch(void* const* d_in, const int* in_sizes, int n_in,
                              void* d_out, int out_size, void* d_ws, size_t ws_size,
                              hipStream_t stream) {
    const float* x  = (const float*)d_in[0];
    const float* Wq = (const float*)d_in[1];
    const float* Wk = (const float*)d_in[2];
    const float* Wv = (const float*)d_in[3];
    const float* Wo = (const float*)d_in[4];
    float* out = (float*)d_out;

    char* ws = (char*)d_ws;
    ushort* xb  = (ushort*)ws; ws += (size_t)8192 * 1024 * 2;   // 16 MB
    ushort* Wqt = (ushort*)ws; ws += (size_t)1536 * 1024 * 2;   // fused [1536][1024]
    ushort* Wot = (ushort*)ws; ws += (size_t)1024 * 512 * 2;
    ushort* Qm  = (ushort*)ws; ws += (size_t)8192 * 512 * 2;
    ushort* Km  = (ushort*)ws; ws += (size_t)8192 * 512 * 2;
    ushort* Vtm = (ushort*)ws; ws += (size_t)8192 * 512 * 2;
    ushort* Om  = xb;  // reuse: xb dead after QKV GEMM

    f32_to_bf16_k<<<8192, 256, 0, stream>>>(x, xb, 2097152);
    transpose_all_k<<<512, 256, 0, stream>>>(Wq, Wk, Wv, Wo, Wqt, Wot);

    // fused QKV GEMM + l2norm(Q,K) + V transpose: -> Qm | Km | Vtm
    gemm_tile_k<0, 1><<<768, 256, 0, stream>>>(xb, Wqt, Qm, Km, Vtm, 8192, 1536, 1024, 12);

    flash_attn_k<<<dim3(32, 32), 256, 0, stream>>>(Qm, Km, Vtm, Om);

    // out projection: [8192][512] x [1024][512]^T -> out (f32)
    gemm_tile_k<1, 0><<<512, 256, 0, stream>>>(Om, Wot, out, nullptr, nullptr, 8192, 1024, 512, 8);
}

// Round 11
// 110.552 us; speedup vs baseline: 1.6769x; 1.0515x over previous
//
#include <hip/hip_runtime.h>
#include <hip/hip_bf16.h>

typedef __attribute__((ext_vector_type(8))) __bf16 bf16x8;
typedef __attribute__((ext_vector_type(4))) __bf16 bf16x4;
typedef __attribute__((ext_vector_type(4))) float f32x4;

#define MFMA16(a, b, c) __builtin_amdgcn_mfma_f32_16x16x32_bf16(a, b, c, 0, 0, 0)

static __device__ __forceinline__ ushort f2b(float f) {
    __bf16 b = (__bf16)f;
    return __builtin_bit_cast(ushort, b);
}
static __device__ __forceinline__ bf16x8 cat44(bf16x4 a, bf16x4 b) {
    bf16x8 r;
    r[0] = a[0]; r[1] = a[1]; r[2] = a[2]; r[3] = a[3];
    r[4] = b[0]; r[5] = b[1]; r[6] = b[2]; r[7] = b[3];
    return r;
}
static __device__ __forceinline__ void gload_lds16(const ushort* g, ushort* l) {
    __builtin_amdgcn_global_load_lds(
        (const __attribute__((address_space(1))) unsigned int*)g,
        (__attribute__((address_space(3))) unsigned int*)l, 16, 0, 0);
}
static __device__ __forceinline__ float exp2_fast(float x) {
    float r;
    asm("v_exp_f32 %0, %1" : "=v"(r) : "v"(x));
    return r;
}

// ---------------- prep: f32->bf16 convert (blocks 0..8191) + W transposes (8192..8703) ----------------
__global__ __launch_bounds__(256)
void prep_k(const float* __restrict__ x, ushort* __restrict__ xb,
            const float* __restrict__ Wq, const float* __restrict__ Wk,
            const float* __restrict__ Wv, const float* __restrict__ Wo,
            ushort* __restrict__ Wqkv, ushort* __restrict__ Wot) {
    const int bid = blockIdx.x;
    const int tid = threadIdx.x;
    if (bid < 8192) {
        int i = bid * 256 + tid;
        float4 v = reinterpret_cast<const float4*>(x)[i];
        ushort4 o;
        o.x = f2b(v.x); o.y = f2b(v.y); o.z = f2b(v.z); o.w = f2b(v.w);
        reinterpret_cast<ushort4*>(xb)[i] = o;
        return;
    }
    __shared__ ushort T[64][72];
    const int bb = bid - 8192;
    const int job = bb >> 7;
    const int t = bb & 127;
    const float* src; ushort* dst; int K, N;
    if (job == 0)      { src = Wq; dst = Wqkv;                       K = 1024; N = 512; }
    else if (job == 1) { src = Wk; dst = Wqkv + (size_t)512 * 1024;  K = 1024; N = 512; }
    else if (job == 2) { src = Wv; dst = Wqkv + (size_t)1024 * 1024; K = 1024; N = 512; }
    else               { src = Wo; dst = Wot;                        K = 512;  N = 1024; }
    const int tn = N >> 6;
    const int bk = t / tn, bn = t - bk * tn;
    const int k0 = bk * 64, n0 = bn * 64;
#pragma unroll
    for (int q = 0; q < 4; ++q) {
        const int lin = tid + 256 * q;
        const int kr = lin >> 4;
        const int n4 = (lin & 15) << 2;
        float4 v = *reinterpret_cast<const float4*>(&src[(size_t)(k0 + kr) * N + n0 + n4]);
        T[n4 + 0][kr] = f2b(v.x);
        T[n4 + 1][kr] = f2b(v.y);
        T[n4 + 2][kr] = f2b(v.z);
        T[n4 + 3][kr] = f2b(v.w);
    }
    __syncthreads();
#pragma unroll
    for (int s = 0; s < 2; ++s) {
        const int lin = tid + 256 * s;
        const int n = lin >> 3;
        const int kc = (lin & 7) << 3;
        ushort4 a, b;
        a.x = T[n][kc + 0]; a.y = T[n][kc + 1]; a.z = T[n][kc + 2]; a.w = T[n][kc + 3];
        b.x = T[n][kc + 4]; b.y = T[n][kc + 5]; b.z = T[n][kc + 6]; b.w = T[n][kc + 7];
        ushort* p = &dst[(size_t)(n0 + n) * K + k0 + kc];
        *reinterpret_cast<ushort4*>(p) = a;
        *reinterpret_cast<ushort4*>(p + 4) = b;
    }
}

// ---------------- tiled GEMM, BK=64 + both-sides XOR swizzle: C = A[M][K] * Bt[N][K]^T ----------------
// 128x128 tile, BK=64 (halves barrier-drain count vs BK=32; 32 MFMA/step),
// LDS [128][64] with 16B-chunk swizzle cc = gc ^ (row&7) (staged pre-swizzled
// source, read with matching XOR) -> ds_read_b128 2-way max (free).
// ROUTE=1 (QKV fused, N=1536): grp0/1 (Q,K) -> per-head row l2norm -> bf16;
// grp2 (V) -> transposed write to Vt[32][64][2048].
template <int F32OUT, int ROUTE>
__global__ __launch_bounds__(256)
void gemm_tile_k(const ushort* __restrict__ A, const ushort* __restrict__ Bt,
                 void* __restrict__ C0, void* __restrict__ C1, void* __restrict__ C2,
                 int M, int N, int K, int nby) {
    __shared__ __align__(16) ushort As[128 * 64];
    __shared__ __align__(16) ushort Bs[128 * 64];
    const int tid = threadIdx.x;
    const int lane = tid & 63;
    const int w = tid >> 6;
    const int l15 = lane & 15, g = lane >> 4;
    const int wr = w >> 1, wc = w & 1;

    // bijective XCD swizzle (gridDim.x % 8 == 0)
    const int nwg = gridDim.x;
    const int cpx = nwg >> 3;
    const int bid = blockIdx.x;
    const int swz = (bid & 7) * cpx + (bid >> 3);
    const int bx = swz / nby, by = swz - bx * nby;
    const int rbase = bx * 128, cbase = by * 128;

    // staging: wave w owns tile rows [32w,32w+32). instr i covers rows 32w+8i..+8.
    // lane l -> row +(l>>3), LDS chunk (l&7); source chunk = (l&7)^(l>>3) (row&7 == l>>3).
    const int lr = lane >> 3;
    const int sc = (lane & 7) ^ lr;
    const ushort* Ap = A + (size_t)(rbase + 32 * w + lr) * K + sc * 8;
    const ushort* Bp = Bt + (size_t)(cbase + 32 * w + lr) * K + sc * 8;
    ushort* AsD = &As[(32 * w) * 64];
    ushort* BsD = &Bs[(32 * w) * 64];

    f32x4 acc[4][4];
#pragma unroll
    for (int m = 0; m < 4; ++m)
#pragma unroll
        for (int n = 0; n < 4; ++n) acc[m][n] = (f32x4){0, 0, 0, 0};

    const int nk = K >> 6;
    for (int kt = 0; kt < nk; ++kt) {
        const int k0 = kt << 6;
        if (kt) __syncthreads();
#pragma unroll
        for (int i = 0; i < 4; ++i) {
            gload_lds16(Ap + (size_t)(8 * i) * K + k0, AsD + (8 * i) * 64);
            gload_lds16(Bp + (size_t)(8 * i) * K + k0, BsD + (8 * i) * 64);
        }
        __syncthreads();
        bf16x8 af[4][2], bfr[4][2];
#pragma unroll
        for (int m = 0; m < 4; ++m) {
            const int row = 64 * wr + 16 * m + l15;
#pragma unroll
            for (int kh = 0; kh < 2; ++kh) {
                const int ch = (g + 4 * kh) ^ (l15 & 7);
                af[m][kh] = *reinterpret_cast<const bf16x8*>(&As[row * 64 + ch * 8]);
            }
        }
#pragma unroll
        for (int n = 0; n < 4; ++n) {
            const int row = 64 * wc + 16 * n + l15;
#pragma unroll
            for (int kh = 0; kh < 2; ++kh) {
                const int ch = (g + 4 * kh) ^ (l15 & 7);
                bfr[n][kh] = *reinterpret_cast<const bf16x8*>(&Bs[row * 64 + ch * 8]);
            }
        }
#pragma unroll
        for (int m = 0; m < 4; ++m)
#pragma unroll
            for (int n = 0; n < 4; ++n) {
                acc[m][n] = MFMA16(af[m][0], bfr[n][0], acc[m][n]);
                acc[m][n] = MFMA16(af[m][1], bfr[n][1], acc[m][n]);
            }
    }

    if (ROUTE) {
        const int col0 = cbase + 64 * wc;     // wave-uniform, 64-aligned => one head
        const int grp = col0 >> 9;            // 0=Q,1=K,2=V
        const int co0 = col0 & 511;
        if (grp == 2) {
            const int h = co0 >> 6;
#pragma unroll
            for (int m = 0; m < 4; ++m) {
                const int row = rbase + 64 * wr + 16 * m + 4 * g;
                const int bb = row >> 11;
                const int tok = row & 2047;
#pragma unroll
                for (int n = 0; n < 4; ++n) {
                    const int d = 16 * n + l15;
                    bf16x4 wv;
#pragma unroll
                    for (int r = 0; r < 4; ++r) wv[r] = (__bf16)acc[m][n][r];
                    ushort* dst = (ushort*)C2 + (((size_t)(bb * 8 + h) * 64 + d) * 2048 + tok);
                    *reinterpret_cast<bf16x4*>(dst) = wv;
                }
            }
        } else {
            ushort* Cg = (ushort*)(grp == 0 ? C0 : C1);
#pragma unroll
            for (int m = 0; m < 4; ++m) {
                f32x4 ss = {0, 0, 0, 0};
#pragma unroll
                for (int n = 0; n < 4; ++n)
#pragma unroll
                    for (int r = 0; r < 4; ++r) ss[r] += acc[m][n][r] * acc[m][n][r];
#pragma unroll
                for (int r = 0; r < 4; ++r) {
                    float s = ss[r];
                    s += __shfl_xor(s, 1);
                    s += __shfl_xor(s, 2);
                    s += __shfl_xor(s, 4);
                    s += __shfl_xor(s, 8);
                    ss[r] = 1.0f / fmaxf(sqrtf(s), 1e-12f);
                }
                const int row = rbase + 64 * wr + 16 * m + 4 * g;
#pragma unroll
                for (int n = 0; n < 4; ++n) {
                    const int co = co0 + 16 * n + l15;
#pragma unroll
                    for (int r = 0; r < 4; ++r)
                        Cg[(size_t)(row + r) * 512 + co] = f2b(acc[m][n][r] * ss[r]);
                }
            }
        }
    } else {
#pragma unroll
        for (int m = 0; m < 4; ++m)
#pragma unroll
            for (int n = 0; n < 4; ++n) {
                const int row = rbase + 64 * wr + 16 * m + 4 * g;
                const int col = cbase + 64 * wc + 16 * n + l15;
                if (F32OUT) {
#pragma unroll
                    for (int r = 0; r < 4; ++r)
                        reinterpret_cast<float*>(C0)[(size_t)(row + r) * N + col] = acc[m][n][r];
                } else {
#pragma unroll
                    for (int r = 0; r < 4; ++r)
                        reinterpret_cast<ushort*>(C0)[(size_t)(row + r) * N + col] = f2b(acc[m][n][r]);
                }
            }
    }
}

// ---------------- causal cosine-sim flash attention (round-8 proven form) ----------------
// 2 waves/block share K/V 64x64 LDS tiles (global_load_lds + 16B-chunk XOR
// swizzle, both-sides). Wave handles q-tiles (c, 127-c); fixed softmax offset 8
// (cos-sim S<=8); exp2-direct; lsum via ones-MFMA; setprio around PV.
__global__ __launch_bounds__(128, 2)
void flash_attn_k(const ushort* __restrict__ Q, const ushort* __restrict__ K,
                  const ushort* __restrict__ Vt, ushort* __restrict__ O) {
    __shared__ __align__(16) ushort Ks[64 * 64];
    __shared__ __align__(16) ushort Vs[64 * 64];
    const int tid = threadIdx.x;      // 0..127
    const int lane = tid & 63;
    const int wave = tid >> 6;
    const int l15 = lane & 15;
    const int g = lane >> 4;
    const int bh = blockIdx.x;
    const int b = bh >> 3, h = bh & 7;
    const int j = blockIdx.y;                   // 0..31
    const int ytrue = (j < 16) ? j : 47 - j;    // balance remap
    const int wglob = ytrue * 2 + wave;         // 0..63
    const int c0 = wglob;
    const int c1 = 127 - wglob;
    const int q0 = c0 * 16 + l15;
    const int q1 = c1 * 16 + l15;
    const int nt0 = (c0 * 16 + 79) >> 6;
    const int nt1 = (c1 * 16 + 79) >> 6;
    const int ntb = ((127 - 2 * ytrue) * 16 + 79) >> 6;  // block max (wave 0)

    const float CEXP = 11.5415603f;  // 8*log2(e)

    const ushort* Qb = Q + (size_t)(b * 2048) * 512 + h * 64;
    const ushort* Kb = K + (size_t)(b * 2048) * 512 + h * 64;
    const ushort* Vb = Vt + (size_t)bh * 64 * 2048;

    const ushort* kSrc[4];
    const ushort* vSrc[4];
    ushort* kDst[4];
    ushort* vDst[4];
#pragma unroll
    for (int i = 0; i < 4; ++i) {
        const int s = tid + 128 * i;
        const int row = s >> 3;
        const int cc = s & 7;
        const int scc = cc ^ (row & 7);
        kSrc[i] = Kb + (size_t)row * 512 + scc * 8;
        vSrc[i] = Vb + (size_t)row * 2048 + scc * 8;
        const int base = (wave * 64 + 128 * i) * 8;
        kDst[i] = &Ks[base];
        vDst[i] = &Vs[base];
    }

    bf16x8 qf0[2], qf1[2];
#pragma unroll
    for (int kh = 0; kh < 2; ++kh) {
        qf0[kh] = *reinterpret_cast<const bf16x8*>(Qb + (size_t)q0 * 512 + 32 * kh + 8 * g);
        qf1[kh] = *reinterpret_cast<const bf16x8*>(Qb + (size_t)q1 * 512 + 32 * kh + 8 * g);
    }

    bf16x8 ones;
#pragma unroll
    for (int i = 0; i < 8; ++i) ones[i] = (__bf16)1.0f;

    f32x4 acc0[4], acc1[4];
#pragma unroll
    for (int d = 0; d < 4; ++d) {
        acc0[d] = (f32x4){0, 0, 0, 0};
        acc1[d] = (f32x4){0, 0, 0, 0};
    }
    f32x4 lac0 = {0, 0, 0, 0}, lac1 = {0, 0, 0, 0};

    for (int t = 0; t < ntb; ++t) {
        if (t) __syncthreads();
#pragma unroll
        for (int i = 0; i < 4; ++i) gload_lds16(kSrc[i] + (size_t)t * 32768, kDst[i]);
#pragma unroll
        for (int i = 0; i < 4; ++i) gload_lds16(vSrc[i] + t * 64, vDst[i]);
        __syncthreads();

        if (t >= nt1) continue;
        const bool act0 = (t < nt0);
        const bool mk0 = (t == nt0 - 1);
        const bool mk1 = (t == nt1 - 1);

        bf16x8 af[4][2];
#pragma unroll
        for (int jt = 0; jt < 4; ++jt)
#pragma unroll
            for (int kh = 0; kh < 2; ++kh) {
                const int row = jt * 16 + l15;
                const int chunk = (g + 4 * kh) ^ (row & 7);
                af[jt][kh] = *reinterpret_cast<const bf16x8*>(&Ks[row * 64 + chunk * 8]);
            }
        bf16x4 vf[4][2][2];
#pragma unroll
        for (int d = 0; d < 4; ++d)
#pragma unroll
            for (int kk = 0; kk < 2; ++kk)
#pragma unroll
                for (int th = 0; th < 2; ++th) {
                    const int dr = d * 16 + l15;
                    const int chunk = ((g >> 1) + 2 * th + 4 * kk) ^ (dr & 7);
                    vf[d][kk][th] = *reinterpret_cast<const bf16x4*>(
                        &Vs[dr * 64 + chunk * 8 + (g & 1) * 4]);
                }

        // QK^T for BOTH tiles first: softmax1 VALU overlaps tile0 MFMA latency
        f32x4 s1[4], s0[4];
#pragma unroll
        for (int jt = 0; jt < 4; ++jt) {
            f32x4 z = {0, 0, 0, 0};
            z = MFMA16(af[jt][0], qf1[0], z);
            s1[jt] = MFMA16(af[jt][1], qf1[1], z);
        }
        if (act0) {
#pragma unroll
            for (int jt = 0; jt < 4; ++jt) {
                f32x4 z = {0, 0, 0, 0};
                z = MFMA16(af[jt][0], qf0[0], z);
                s0[jt] = MFMA16(af[jt][1], qf0[1], z);
            }
        }

        bf16x8 pt1[2];
#pragma unroll
        for (int jt = 0; jt < 4; ++jt) {
#pragma unroll
            for (int r = 0; r < 4; ++r) {
                float p = exp2_fast(fmaf(s1[jt][r], CEXP, -CEXP));
                if (mk1) {
                    int jj = t * 64 + jt * 16 + 4 * g + r;
                    p = (jj <= q1) ? p : 0.0f;
                }
                pt1[jt >> 1][(jt & 1) * 4 + r] = (__bf16)p;
            }
        }

        __builtin_amdgcn_s_setprio(1);
#pragma unroll
        for (int d = 0; d < 4; ++d) {
            bf16x8 v0 = cat44(vf[d][0][0], vf[d][0][1]);
            bf16x8 v1 = cat44(vf[d][1][0], vf[d][1][1]);
            acc1[d] = MFMA16(v0, pt1[0], acc1[d]);
            acc1[d] = MFMA16(v1, pt1[1], acc1[d]);
        }
        lac1 = MFMA16(ones, pt1[0], lac1);
        lac1 = MFMA16(ones, pt1[1], lac1);
        __builtin_amdgcn_s_setprio(0);

        if (act0) {
            bf16x8 pt0[2];
#pragma unroll
            for (int jt = 0; jt < 4; ++jt) {
#pragma unroll
                for (int r = 0; r < 4; ++r) {
                    float p = exp2_fast(fmaf(s0[jt][r], CEXP, -CEXP));
                    if (mk0) {
                        int jj = t * 64 + jt * 16 + 4 * g + r;
                        p = (jj <= q0) ? p : 0.0f;
                    }
                    pt0[jt >> 1][(jt & 1) * 4 + r] = (__bf16)p;
                }
            }
            __builtin_amdgcn_s_setprio(1);
#pragma unroll
            for (int d = 0; d < 4; ++d) {
                bf16x8 v0 = cat44(vf[d][0][0], vf[d][0][1]);
                bf16x8 v1 = cat44(vf[d][1][0], vf[d][1][1]);
                acc0[d] = MFMA16(v0, pt0[0], acc0[d]);
                acc0[d] = MFMA16(v1, pt0[1], acc0[d]);
            }
            lac0 = MFMA16(ones, pt0[0], lac0);
            lac0 = MFMA16(ones, pt0[1], lac0);
            __builtin_amdgcn_s_setprio(0);
        }
    }

    auto fin = [&](f32x4 (&acc)[4], float ls, int qr) {
        float inv = 1.0f / ls;
        ushort* Ob = O + (size_t)(b * 2048 + qr) * 512 + h * 64;
#pragma unroll
        for (int d = 0; d < 4; ++d) {
            bf16x4 w;
#pragma unroll
            for (int r = 0; r < 4; ++r) w[r] = (__bf16)(acc[d][r] * inv);
            *reinterpret_cast<bf16x4*>(Ob + d * 16 + 4 * g) = w;
        }
    };
    fin(acc1, lac1[0], q1);
    fin(acc0, lac0[0], q0);
}

extern "C" void kernel_launch(void* const* d_in, const int* in_sizes, int n_in,
                              void* d_out, int out_size, void* d_ws, size_t ws_size,
                              hipStream_t stream) {
    const float* x  = (const float*)d_in[0];
    const float* Wq = (const float*)d_in[1];
    const float* Wk = (const float*)d_in[2];
    const float* Wv = (const float*)d_in[3];
    const float* Wo = (const float*)d_in[4];
    float* out = (float*)d_out;

    char* ws = (char*)d_ws;
    ushort* xb  = (ushort*)ws; ws += (size_t)8192 * 1024 * 2;   // 16 MB
    ushort* Wqt = (ushort*)ws; ws += (size_t)1536 * 1024 * 2;   // fused [1536][1024]
    ushort* Wot = (ushort*)ws; ws += (size_t)1024 * 512 * 2;
    ushort* Qm  = (ushort*)ws; ws += (size_t)8192 * 512 * 2;
    ushort* Km  = (ushort*)ws; ws += (size_t)8192 * 512 * 2;
    ushort* Vtm = (ushort*)ws; ws += (size_t)8192 * 512 * 2;
    ushort* Om  = xb;  // reuse: xb dead after QKV GEMM

    // convert x + all weight transposes in one launch
    prep_k<<<8704, 256, 0, stream>>>(x, xb, Wq, Wk, Wv, Wo, Wqt, Wot);

    // fused QKV GEMM + l2norm(Q,K) + V transpose: -> Qm | Km | Vtm
    gemm_tile_k<0, 1><<<768, 256, 0, stream>>>(xb, Wqt, Qm, Km, Vtm, 8192, 1536, 1024, 12);

    flash_attn_k<<<dim3(32, 32), 128, 0, stream>>>(Qm, Km, Vtm, Om);

    // out projection: [8192][512] x [1024][512]^T -> out (f32)
    gemm_tile_k<1, 0><<<512, 256, 0, stream>>>(Om, Wot, out, nullptr, nullptr, 8192, 1024, 512, 8);
}

// Round 12
// 107.510 us; speedup vs baseline: 1.7244x; 1.0283x over previous
//
#include <hip/hip_runtime.h>
#include <hip/hip_bf16.h>

typedef __attribute__((ext_vector_type(8))) __bf16 bf16x8;
typedef __attribute__((ext_vector_type(4))) __bf16 bf16x4;
typedef __attribute__((ext_vector_type(4))) float f32x4;

#define MFMA16(a, b, c) __builtin_amdgcn_mfma_f32_16x16x32_bf16(a, b, c, 0, 0, 0)

static __device__ __forceinline__ ushort f2b(float f) {
    __bf16 b = (__bf16)f;
    return __builtin_bit_cast(ushort, b);
}
static __device__ __forceinline__ bf16x8 cat44(bf16x4 a, bf16x4 b) {
    bf16x8 r;
    r[0] = a[0]; r[1] = a[1]; r[2] = a[2]; r[3] = a[3];
    r[4] = b[0]; r[5] = b[1]; r[6] = b[2]; r[7] = b[3];
    return r;
}
static __device__ __forceinline__ void gload_lds16(const ushort* g, ushort* l) {
    __builtin_amdgcn_global_load_lds(
        (const __attribute__((address_space(1))) unsigned int*)g,
        (__attribute__((address_space(3))) unsigned int*)l, 16, 0, 0);
}
static __device__ __forceinline__ float exp2_fast(float x) {
    float r;
    asm("v_exp_f32 %0, %1" : "=v"(r) : "v"(x));
    return r;
}

// ---------------- prep: f32->bf16 convert (blocks 0..8191) + W transposes (8192..8703) ----------------
__global__ __launch_bounds__(256)
void prep_k(const float* __restrict__ x, ushort* __restrict__ xb,
            const float* __restrict__ Wq, const float* __restrict__ Wk,
            const float* __restrict__ Wv, const float* __restrict__ Wo,
            ushort* __restrict__ Wqkv, ushort* __restrict__ Wot) {
    const int bid = blockIdx.x;
    const int tid = threadIdx.x;
    if (bid < 8192) {
        int i = bid * 256 + tid;
        float4 v = reinterpret_cast<const float4*>(x)[i];
        ushort4 o;
        o.x = f2b(v.x); o.y = f2b(v.y); o.z = f2b(v.z); o.w = f2b(v.w);
        reinterpret_cast<ushort4*>(xb)[i] = o;
        return;
    }
    __shared__ ushort T[64][72];
    const int bb = bid - 8192;
    const int job = bb >> 7;
    const int t = bb & 127;
    const float* src; ushort* dst; int K, N;
    if (job == 0)      { src = Wq; dst = Wqkv;                       K = 1024; N = 512; }
    else if (job == 1) { src = Wk; dst = Wqkv + (size_t)512 * 1024;  K = 1024; N = 512; }
    else if (job == 2) { src = Wv; dst = Wqkv + (size_t)1024 * 1024; K = 1024; N = 512; }
    else               { src = Wo; dst = Wot;                        K = 512;  N = 1024; }
    const int tn = N >> 6;
    const int bk = t / tn, bn = t - bk * tn;
    const int k0 = bk * 64, n0 = bn * 64;
#pragma unroll
    for (int q = 0; q < 4; ++q) {
        const int lin = tid + 256 * q;
        const int kr = lin >> 4;
        const int n4 = (lin & 15) << 2;
        float4 v = *reinterpret_cast<const float4*>(&src[(size_t)(k0 + kr) * N + n0 + n4]);
        T[n4 + 0][kr] = f2b(v.x);
        T[n4 + 1][kr] = f2b(v.y);
        T[n4 + 2][kr] = f2b(v.z);
        T[n4 + 3][kr] = f2b(v.w);
    }
    __syncthreads();
#pragma unroll
    for (int s = 0; s < 2; ++s) {
        const int lin = tid + 256 * s;
        const int n = lin >> 3;
        const int kc = (lin & 7) << 3;
        ushort4 a, b;
        a.x = T[n][kc + 0]; a.y = T[n][kc + 1]; a.z = T[n][kc + 2]; a.w = T[n][kc + 3];
        b.x = T[n][kc + 4]; b.y = T[n][kc + 5]; b.z = T[n][kc + 6]; b.w = T[n][kc + 7];
        ushort* p = &dst[(size_t)(n0 + n) * K + k0 + kc];
        *reinterpret_cast<ushort4*>(p) = a;
        *reinterpret_cast<ushort4*>(p + 4) = b;
    }
}

// ---------------- tiled GEMM, BK=64 + both-sides XOR swizzle: C = A[M][K] * Bt[N][K]^T ----------------
// ROUTE=1 (QKV fused, N=1536): grp0/1 (Q,K) -> per-head row l2norm -> bf16;
// grp2 (V) -> transposed write to Vt[32][64][2048].
template <int F32OUT, int ROUTE>
__global__ __launch_bounds__(256)
void gemm_tile_k(const ushort* __restrict__ A, const ushort* __restrict__ Bt,
                 void* __restrict__ C0, void* __restrict__ C1, void* __restrict__ C2,
                 int M, int N, int K, int nby) {
    __shared__ __align__(16) ushort As[128 * 64];
    __shared__ __align__(16) ushort Bs[128 * 64];
    const int tid = threadIdx.x;
    const int lane = tid & 63;
    const int w = tid >> 6;
    const int l15 = lane & 15, g = lane >> 4;
    const int wr = w >> 1, wc = w & 1;

    const int nwg = gridDim.x;
    const int cpx = nwg >> 3;
    const int bid = blockIdx.x;
    const int swz = (bid & 7) * cpx + (bid >> 3);
    const int bx = swz / nby, by = swz - bx * nby;
    const int rbase = bx * 128, cbase = by * 128;

    const int lr = lane >> 3;
    const int sc = (lane & 7) ^ lr;
    const ushort* Ap = A + (size_t)(rbase + 32 * w + lr) * K + sc * 8;
    const ushort* Bp = Bt + (size_t)(cbase + 32 * w + lr) * K + sc * 8;
    ushort* AsD = &As[(32 * w) * 64];
    ushort* BsD = &Bs[(32 * w) * 64];

    f32x4 acc[4][4];
#pragma unroll
    for (int m = 0; m < 4; ++m)
#pragma unroll
        for (int n = 0; n < 4; ++n) acc[m][n] = (f32x4){0, 0, 0, 0};

    const int nk = K >> 6;
    for (int kt = 0; kt < nk; ++kt) {
        const int k0 = kt << 6;
        if (kt) __syncthreads();
#pragma unroll
        for (int i = 0; i < 4; ++i) {
            gload_lds16(Ap + (size_t)(8 * i) * K + k0, AsD + (8 * i) * 64);
            gload_lds16(Bp + (size_t)(8 * i) * K + k0, BsD + (8 * i) * 64);
        }
        __syncthreads();
        bf16x8 af[4][2], bfr[4][2];
#pragma unroll
        for (int m = 0; m < 4; ++m) {
            const int row = 64 * wr + 16 * m + l15;
#pragma unroll
            for (int kh = 0; kh < 2; ++kh) {
                const int ch = (g + 4 * kh) ^ (l15 & 7);
                af[m][kh] = *reinterpret_cast<const bf16x8*>(&As[row * 64 + ch * 8]);
            }
        }
#pragma unroll
        for (int n = 0; n < 4; ++n) {
            const int row = 64 * wc + 16 * n + l15;
#pragma unroll
            for (int kh = 0; kh < 2; ++kh) {
                const int ch = (g + 4 * kh) ^ (l15 & 7);
                bfr[n][kh] = *reinterpret_cast<const bf16x8*>(&Bs[row * 64 + ch * 8]);
            }
        }
#pragma unroll
        for (int m = 0; m < 4; ++m)
#pragma unroll
            for (int n = 0; n < 4; ++n) {
                acc[m][n] = MFMA16(af[m][0], bfr[n][0], acc[m][n]);
                acc[m][n] = MFMA16(af[m][1], bfr[n][1], acc[m][n]);
            }
    }

    if (ROUTE) {
        const int col0 = cbase + 64 * wc;
        const int grp = col0 >> 9;
        const int co0 = col0 & 511;
        if (grp == 2) {
            const int h = co0 >> 6;
#pragma unroll
            for (int m = 0; m < 4; ++m) {
                const int row = rbase + 64 * wr + 16 * m + 4 * g;
                const int bb = row >> 11;
                const int tok = row & 2047;
#pragma unroll
                for (int n = 0; n < 4; ++n) {
                    const int d = 16 * n + l15;
                    bf16x4 wv;
#pragma unroll
                    for (int r = 0; r < 4; ++r) wv[r] = (__bf16)acc[m][n][r];
                    ushort* dst = (ushort*)C2 + (((size_t)(bb * 8 + h) * 64 + d) * 2048 + tok);
                    *reinterpret_cast<bf16x4*>(dst) = wv;
                }
            }
        } else {
            ushort* Cg = (ushort*)(grp == 0 ? C0 : C1);
#pragma unroll
            for (int m = 0; m < 4; ++m) {
                f32x4 ss = {0, 0, 0, 0};
#pragma unroll
                for (int n = 0; n < 4; ++n)
#pragma unroll
                    for (int r = 0; r < 4; ++r) ss[r] += acc[m][n][r] * acc[m][n][r];
#pragma unroll
                for (int r = 0; r < 4; ++r) {
                    float s = ss[r];
                    s += __shfl_xor(s, 1);
                    s += __shfl_xor(s, 2);
                    s += __shfl_xor(s, 4);
                    s += __shfl_xor(s, 8);
                    ss[r] = 1.0f / fmaxf(sqrtf(s), 1e-12f);
                }
                const int row = rbase + 64 * wr + 16 * m + 4 * g;
#pragma unroll
                for (int n = 0; n < 4; ++n) {
                    const int co = co0 + 16 * n + l15;
#pragma unroll
                    for (int r = 0; r < 4; ++r)
                        Cg[(size_t)(row + r) * 512 + co] = f2b(acc[m][n][r] * ss[r]);
                }
            }
        }
    } else {
#pragma unroll
        for (int m = 0; m < 4; ++m)
#pragma unroll
            for (int n = 0; n < 4; ++n) {
                const int row = rbase + 64 * wr + 16 * m + 4 * g;
                const int col = cbase + 64 * wc + 16 * n + l15;
                if (F32OUT) {
#pragma unroll
                    for (int r = 0; r < 4; ++r)
                        reinterpret_cast<float*>(C0)[(size_t)(row + r) * N + col] = acc[m][n][r];
                } else {
#pragma unroll
                    for (int r = 0; r < 4; ++r)
                        reinterpret_cast<ushort*>(C0)[(size_t)(row + r) * N + col] = f2b(acc[m][n][r]);
                }
            }
    }
}

// ---------------- causal cosine-sim flash attention (v9: KVBLK=128, drain amortized) ----------------
// 2 waves/block share TWO 64x64 K/V sub-tiles per step (32 KB LDS, 4 blocks/CU).
// One barrier pair per 128 kv rows (was per 64) -> stage/drain stall halved.
// Fixed softmax offset 8; exp2-direct; lsum via ones-MFMA; setprio around PV.
__global__ __launch_bounds__(128, 2)
void flash_attn_k(const ushort* __restrict__ Q, const ushort* __restrict__ K,
                  const ushort* __restrict__ Vt, ushort* __restrict__ O) {
    __shared__ __align__(16) ushort Ks[2][64 * 64];
    __shared__ __align__(16) ushort Vs[2][64 * 64];
    const int tid = threadIdx.x;      // 0..127
    const int lane = tid & 63;
    const int wave = tid >> 6;
    const int l15 = lane & 15;
    const int g = lane >> 4;
    const int bh = blockIdx.x;
    const int b = bh >> 3, h = bh & 7;
    const int j = blockIdx.y;                   // 0..31
    const int ytrue = (j < 16) ? j : 47 - j;    // balance remap
    const int wglob = ytrue * 2 + wave;         // 0..63
    const int c0 = wglob;
    const int c1 = 127 - wglob;
    const int q0 = c0 * 16 + l15;
    const int q1 = c1 * 16 + l15;
    const int nt0 = (c0 * 16 + 79) >> 6;        // 64-row tiles for q-tile 0
    const int nt1 = (c1 * 16 + 79) >> 6;
    const int ntb = ((127 - 2 * ytrue) * 16 + 79) >> 6;  // block max in 64-units
    const int ntb2 = (ntb + 1) >> 1;            // 128-row steps

    const float CEXP = 11.5415603f;  // 8*log2(e)

    const ushort* Qb = Q + (size_t)(b * 2048) * 512 + h * 64;
    const ushort* Kb = K + (size_t)(b * 2048) * 512 + h * 64;
    const ushort* Vb = Vt + (size_t)bh * 64 * 2048;

    // staging geometry: 64x64 tile = 512 x 16B slots; thread covers slots {tid+128i}
    const ushort* kSrc[4];
    const ushort* vSrc[4];
    int dOff[4];
#pragma unroll
    for (int i = 0; i < 4; ++i) {
        const int s = tid + 128 * i;
        const int row = s >> 3;
        const int cc = s & 7;
        const int scc = cc ^ (row & 7);
        kSrc[i] = Kb + (size_t)row * 512 + scc * 8;
        vSrc[i] = Vb + (size_t)row * 2048 + scc * 8;
        dOff[i] = (wave * 64 + 128 * i) * 8;
    }

    bf16x8 qf0[2], qf1[2];
#pragma unroll
    for (int kh = 0; kh < 2; ++kh) {
        qf0[kh] = *reinterpret_cast<const bf16x8*>(Qb + (size_t)q0 * 512 + 32 * kh + 8 * g);
        qf1[kh] = *reinterpret_cast<const bf16x8*>(Qb + (size_t)q1 * 512 + 32 * kh + 8 * g);
    }

    bf16x8 ones;
#pragma unroll
    for (int i = 0; i < 8; ++i) ones[i] = (__bf16)1.0f;

    f32x4 acc0[4], acc1[4];
#pragma unroll
    for (int d = 0; d < 4; ++d) {
        acc0[d] = (f32x4){0, 0, 0, 0};
        acc1[d] = (f32x4){0, 0, 0, 0};
    }
    f32x4 lac0 = {0, 0, 0, 0}, lac1 = {0, 0, 0, 0};

    for (int t = 0; t < ntb2; ++t) {
        if (t) __syncthreads();
        // stage sub-tile 0 (kv rows t*128..+64) and sub-tile 1 (+64..+128)
        {
            const size_t kofs = (size_t)t * 65536;          // 128 rows * 512
            const int vofs = t * 128;
#pragma unroll
            for (int i = 0; i < 4; ++i) gload_lds16(kSrc[i] + kofs, &Ks[0][dOff[i]]);
#pragma unroll
            for (int i = 0; i < 4; ++i) gload_lds16(vSrc[i] + vofs, &Vs[0][dOff[i]]);
            if (2 * t + 1 < ntb) {
#pragma unroll
                for (int i = 0; i < 4; ++i) gload_lds16(kSrc[i] + kofs + 32768, &Ks[1][dOff[i]]);
#pragma unroll
                for (int i = 0; i < 4; ++i) gload_lds16(vSrc[i] + vofs + 64, &Vs[1][dOff[i]]);
            }
        }
        __syncthreads();

#pragma unroll
        for (int sub = 0; sub < 2; ++sub) {
            const int u = 2 * t + sub;               // 64-row tile index
            if (u >= nt1) break;                     // wave-uniform
            const ushort* Kt = Ks[sub];
            const ushort* Vtl = Vs[sub];
            const bool act0 = (u < nt0);
            const bool mk0 = (u == nt0 - 1);
            const bool mk1 = (u == nt1 - 1);

            bf16x8 af[4][2];
#pragma unroll
            for (int jt = 0; jt < 4; ++jt)
#pragma unroll
                for (int kh = 0; kh < 2; ++kh) {
                    const int row = jt * 16 + l15;
                    const int chunk = (g + 4 * kh) ^ (row & 7);
                    af[jt][kh] = *reinterpret_cast<const bf16x8*>(&Kt[row * 64 + chunk * 8]);
                }
            bf16x4 vf[4][2][2];
#pragma unroll
            for (int d = 0; d < 4; ++d)
#pragma unroll
                for (int kk = 0; kk < 2; ++kk)
#pragma unroll
                    for (int th = 0; th < 2; ++th) {
                        const int dr = d * 16 + l15;
                        const int chunk = ((g >> 1) + 2 * th + 4 * kk) ^ (dr & 7);
                        vf[d][kk][th] = *reinterpret_cast<const bf16x4*>(
                            &Vtl[dr * 64 + chunk * 8 + (g & 1) * 4]);
                    }

            // QK^T for BOTH q-tiles first
            f32x4 s1[4], s0[4];
#pragma unroll
            for (int jt = 0; jt < 4; ++jt) {
                f32x4 z = {0, 0, 0, 0};
                z = MFMA16(af[jt][0], qf1[0], z);
                s1[jt] = MFMA16(af[jt][1], qf1[1], z);
            }
            if (act0) {
#pragma unroll
                for (int jt = 0; jt < 4; ++jt) {
                    f32x4 z = {0, 0, 0, 0};
                    z = MFMA16(af[jt][0], qf0[0], z);
                    s0[jt] = MFMA16(af[jt][1], qf0[1], z);
                }
            }

            bf16x8 pt1[2];
#pragma unroll
            for (int jt = 0; jt < 4; ++jt) {
#pragma unroll
                for (int r = 0; r < 4; ++r) {
                    float p = exp2_fast(fmaf(s1[jt][r], CEXP, -CEXP));
                    if (mk1) {
                        int jj = u * 64 + jt * 16 + 4 * g + r;
                        p = (jj <= q1) ? p : 0.0f;
                    }
                    pt1[jt >> 1][(jt & 1) * 4 + r] = (__bf16)p;
                }
            }

            __builtin_amdgcn_s_setprio(1);
#pragma unroll
            for (int d = 0; d < 4; ++d) {
                bf16x8 v0 = cat44(vf[d][0][0], vf[d][0][1]);
                bf16x8 v1 = cat44(vf[d][1][0], vf[d][1][1]);
                acc1[d] = MFMA16(v0, pt1[0], acc1[d]);
                acc1[d] = MFMA16(v1, pt1[1], acc1[d]);
            }
            lac1 = MFMA16(ones, pt1[0], lac1);
            lac1 = MFMA16(ones, pt1[1], lac1);
            __builtin_amdgcn_s_setprio(0);

            if (act0) {
                bf16x8 pt0[2];
#pragma unroll
                for (int jt = 0; jt < 4; ++jt) {
#pragma unroll
                    for (int r = 0; r < 4; ++r) {
                        float p = exp2_fast(fmaf(s0[jt][r], CEXP, -CEXP));
                        if (mk0) {
                            int jj = u * 64 + jt * 16 + 4 * g + r;
                            p = (jj <= q0) ? p : 0.0f;
                        }
                        pt0[jt >> 1][(jt & 1) * 4 + r] = (__bf16)p;
                    }
                }
                __builtin_amdgcn_s_setprio(1);
#pragma unroll
                for (int d = 0; d < 4; ++d) {
                    bf16x8 v0 = cat44(vf[d][0][0], vf[d][0][1]);
                    bf16x8 v1 = cat44(vf[d][1][0], vf[d][1][1]);
                    acc0[d] = MFMA16(v0, pt0[0], acc0[d]);
                    acc0[d] = MFMA16(v1, pt0[1], acc0[d]);
                }
                lac0 = MFMA16(ones, pt0[0], lac0);
                lac0 = MFMA16(ones, pt0[1], lac0);
                __builtin_amdgcn_s_setprio(0);
            }
        }
    }

    auto fin = [&](f32x4 (&acc)[4], float ls, int qr) {
        float inv = 1.0f / ls;
        ushort* Ob = O + (size_t)(b * 2048 + qr) * 512 + h * 64;
#pragma unroll
        for (int d = 0; d < 4; ++d) {
            bf16x4 w;
#pragma unroll
            for (int r = 0; r < 4; ++r) w[r] = (__bf16)(acc[d][r] * inv);
            *reinterpret_cast<bf16x4*>(Ob + d * 16 + 4 * g) = w;
        }
    };
    fin(acc1, lac1[0], q1);
    fin(acc0, lac0[0], q0);
}

extern "C" void kernel_launch(void* const* d_in, const int* in_sizes, int n_in,
                              void* d_out, int out_size, void* d_ws, size_t ws_size,
                              hipStream_t stream) {
    const float* x  = (const float*)d_in[0];
    const float* Wq = (const float*)d_in[1];
    const float* Wk = (const float*)d_in[2];
    const float* Wv = (const float*)d_in[3];
    const float* Wo = (const float*)d_in[4];
    float* out = (float*)d_out;

    char* ws = (char*)d_ws;
    ushort* xb  = (ushort*)ws; ws += (size_t)8192 * 1024 * 2;   // 16 MB
    ushort* Wqt = (ushort*)ws; ws += (size_t)1536 * 1024 * 2;   // fused [1536][1024]
    ushort* Wot = (ushort*)ws; ws += (size_t)1024 * 512 * 2;
    ushort* Qm  = (ushort*)ws; ws += (size_t)8192 * 512 * 2;
    ushort* Km  = (ushort*)ws; ws += (size_t)8192 * 512 * 2;
    ushort* Vtm = (ushort*)ws; ws += (size_t)8192 * 512 * 2;
    ushort* Om  = xb;  // reuse: xb dead after QKV GEMM

    prep_k<<<8704, 256, 0, stream>>>(x, xb, Wq, Wk, Wv, Wo, Wqt, Wot);

    // fused QKV GEMM + l2norm(Q,K) + V transpose: -> Qm | Km | Vtm
    gemm_tile_k<0, 1><<<768, 256, 0, stream>>>(xb, Wqt, Qm, Km, Vtm, 8192, 1536, 1024, 12);

    flash_attn_k<<<dim3(32, 32), 128, 0, stream>>>(Qm, Km, Vtm, Om);

    // out projection: [8192][512] x [1024][512]^T -> out (f32)
    gemm_tile_k<1, 0><<<512, 256, 0, stream>>>(Om, Wot, out, nullptr, nullptr, 8192, 1024, 512, 8);
}